// Round 1
// baseline (130.716 us; speedup 1.0000x reference)
//
#include <hip/hip_runtime.h>

#define NN   67   // N_OUT + N_HID
#define NOUT 3
#define NIN  4

#if __has_builtin(__builtin_amdgcn_exp2f)
  #define EXP2F __builtin_amdgcn_exp2f
#else
  #define EXP2F exp2f
#endif
#if __has_builtin(__builtin_amdgcn_rcpf)
  #define RCPF __builtin_amdgcn_rcpf
#else
  #define RCPF(x) (1.0f/(x))
#endif

// tanh(x) = 1 - 2/(exp(2x)+1); exp(2x) = exp2(x * 2*log2(e))
// v_exp_f32 + v_rcp_f32: ~2 trans + 3 VALU. Abs err ~2e-7, saturates to +-1.
__device__ __forceinline__ float tanh_fast(float x) {
    float e = EXP2F(x * 2.885390081777927f);
    float r = RCPF(e + 1.0f);
    return __builtin_fmaf(-2.0f, r, 1.0f);
}

__global__ __launch_bounds__(256)
void rnn_agg_kernel(const float* __restrict__ inputs,
                    const float* __restrict__ Win,
                    const float* __restrict__ Wrec,
                    const float* __restrict__ bias,
                    const float* __restrict__ resp,
                    const float* __restrict__ hasin,
                    const int*   __restrict__ np_ptr,
                    float*       __restrict__ out,
                    int total)
{
    int pix = blockIdx.x * blockDim.x + threadIdx.x;
    if (pix >= total) return;
    const int np = np_ptr[0];

    if (np < 1) {   // reference: activs stays zero
        #pragma unroll
        for (int c = 0; c < NOUT; ++c) out[pix * NOUT + c] = 0.0f;
        return;
    }

    // coalesced 16B input load (one pixel's 4 features)
    const float4 x = reinterpret_cast<const float4*>(inputs)[pix];

    float activs[NN];   // fully static indexing -> stays in VGPRs

    // ---- pass 0: recurrent term is exactly zero (activs==0) ----
    #pragma unroll
    for (int j = 0; j < NN; ++j) {
        float agg = x.x * Win[0 * NN + j];                 // uniform idx -> s_load
        agg = __builtin_fmaf(x.y, Win[1 * NN + j], agg);
        agg = __builtin_fmaf(x.z, Win[2 * NN + j], agg);
        agg = __builtin_fmaf(x.w, Win[3 * NN + j], agg);
        activs[j] = hasin[j] * tanh_fast(__builtin_fmaf(resp[j], agg, bias[j]));
    }

    // ---- middle passes (only if np > 2; cold at np==2) ----
    // j-loop NOT unrolled -> newa[] is runtime-indexed -> lives in scratch,
    // keeping hot-path VGPR count low. k-loop unrolled -> activs[] stays in regs.
    for (int p = 1; p < np - 1; ++p) {
        float newa[NN];
        #pragma unroll 1
        for (int j = 0; j < NN; ++j) {
            float agg = x.x * Win[0 * NN + j];
            agg = __builtin_fmaf(x.y, Win[1 * NN + j], agg);
            agg = __builtin_fmaf(x.z, Win[2 * NN + j], agg);
            agg = __builtin_fmaf(x.w, Win[3 * NN + j], agg);
            #pragma unroll
            for (int k = 0; k < NN; ++k)
                agg = __builtin_fmaf(activs[k], Wrec[k * NN + j], agg);
            newa[j] = hasin[j] * tanh_fast(__builtin_fmaf(resp[j], agg, bias[j]));
        }
        #pragma unroll
        for (int j = 0; j < NN; ++j) activs[j] = newa[j];
    }

    // ---- final pass: only the NOUT output columns are ever read ----
    if (np >= 2) {
        #pragma unroll
        for (int c = 0; c < NOUT; ++c) {
            float agg = x.x * Win[0 * NN + c];
            agg = __builtin_fmaf(x.y, Win[1 * NN + c], agg);
            agg = __builtin_fmaf(x.z, Win[2 * NN + c], agg);
            agg = __builtin_fmaf(x.w, Win[3 * NN + c], agg);
            #pragma unroll
            for (int k = 0; k < NN; ++k)
                agg = __builtin_fmaf(activs[k], Wrec[k * NN + c], agg);
            out[pix * NOUT + c] = hasin[c] * tanh_fast(__builtin_fmaf(resp[c], agg, bias[c]));
        }
    } else {        // np == 1: output is pass-0 activs[:3]
        #pragma unroll
        for (int c = 0; c < NOUT; ++c) out[pix * NOUT + c] = activs[c];
    }
}

extern "C" void kernel_launch(void* const* d_in, const int* in_sizes, int n_in,
                              void* d_out, int out_size, void* d_ws, size_t ws_size,
                              hipStream_t stream) {
    const float* inputs = (const float*)d_in[0];
    const float* Win    = (const float*)d_in[1];
    const float* Wrec   = (const float*)d_in[2];
    const float* bias   = (const float*)d_in[3];
    const float* resp   = (const float*)d_in[4];
    const float* hasin  = (const float*)d_in[5];
    const int*   np     = (const int*)d_in[6];
    float*       out    = (float*)d_out;

    const int total = in_sizes[0] / NIN;      // H*W pixels
    const int block = 256;
    const int grid  = (total + block - 1) / block;
    rnn_agg_kernel<<<grid, block, 0, stream>>>(inputs, Win, Wrec, bias, resp,
                                               hasin, np, out, total);
}

// Round 3
// 105.107 us; speedup vs baseline: 1.2436x; 1.2436x over previous
//
#include <hip/hip_runtime.h>

#define NN   67   // N_OUT + N_HID
#define NOUT 3
#define NIN  4
#define PKW  16                      // floats per neuron in packed blob
#define PK_BYTES (NN * PKW * 4)
#define C2   2.885390081777927f      // 2*log2(e)

#if __has_builtin(__builtin_amdgcn_exp2f)
  #define EXP2F __builtin_amdgcn_exp2f
#else
  #define EXP2F exp2f
#endif
#if __has_builtin(__builtin_amdgcn_rcpf)
  #define RCPF __builtin_amdgcn_rcpf
#else
  #define RCPF(x) (1.0f/(x))
#endif

// tanh(y) with arg = 2*log2(e)*y already applied: tanh = 1 - 2*rcp(exp2(arg)+1)
__device__ __forceinline__ float tanh_sc(float arg) {
    float e = EXP2F(arg);
    float r = RCPF(e + 1.0f);
    return __builtin_fmaf(-2.0f, r, 1.0f);
}

// Pack per-neuron data: {Win[0..3][j], resp2, bias2, Wrec[j][0..2], pad×7}
// resp2 = hasin*resp*C2, bias2 = hasin*bias*C2  (hasin ∈ {0,1}: h*tanh(y)=tanh(h*y))
__global__ void pack_kernel(const float* __restrict__ Win,
                            const float* __restrict__ Wrec,
                            const float* __restrict__ bias,
                            const float* __restrict__ resp,
                            const float* __restrict__ hasin,
                            float* __restrict__ pk)
{
    int j = threadIdx.x;
    if (j < NN) {
        float h = hasin[j];
        float* p = pk + j * PKW;
        p[0] = Win[0*NN + j]; p[1] = Win[1*NN + j];
        p[2] = Win[2*NN + j]; p[3] = Win[3*NN + j];
        p[4] = resp[j] * h * C2;
        p[5] = bias[j] * h * C2;
        p[6] = Wrec[j*NN + 0]; p[7] = Wrec[j*NN + 1]; p[8] = Wrec[j*NN + 2];
        p[9]=p[10]=p[11]=p[12]=p[13]=p[14]=p[15] = 0.f;
    }
}

template<int P>
__global__ __launch_bounds__(256)
void rnn_fused(const float* __restrict__ inputs,
               const float* __restrict__ pk,
               const float* __restrict__ Wrec,
               const int*   __restrict__ np_ptr,
               float*       __restrict__ out,
               int total)
{
    const int np   = np_ptr[0];                       // uniform
    const int base = blockIdx.x * (256 * P) + threadIdx.x;

    int    pix[P];
    float4 x[P];
#pragma unroll
    for (int p = 0; p < P; ++p) {                     // coalesced 16B loads
        pix[p] = base + p * 256;
        int idx = pix[p] < total ? pix[p] : total - 1;
        x[p] = reinterpret_cast<const float4*>(inputs)[idx];
    }

    float res[P][NOUT];

    if (np == 2) {
        // ---- HOT PATH: pass0 fused into final; a_j dies immediately ----
        float acc[P][NOUT];
#pragma unroll
        for (int p = 0; p < P; ++p)
#pragma unroll
            for (int c = 0; c < NOUT; ++c) {          // final-pass x@Win[:,c] term
                const float* q = pk + c * PKW;
                float a = x[p].x * q[0];
                a = __builtin_fmaf(x[p].y, q[1], a);
                a = __builtin_fmaf(x[p].z, q[2], a);
                a = __builtin_fmaf(x[p].w, q[3], a);
                acc[p][c] = a;
            }
#pragma unroll
        for (int j = 0; j < NN; ++j) {
            const float* q = pk + j * PKW;            // uniform addr -> s_load
            const float w0 = q[0], w1 = q[1], w2 = q[2], w3 = q[3];
            const float r2 = q[4], b2 = q[5];
            const float wr0 = q[6], wr1 = q[7], wr2 = q[8];
#pragma unroll
            for (int p = 0; p < P; ++p) {
                float agg = x[p].x * w0;
                agg = __builtin_fmaf(x[p].y, w1, agg);
                agg = __builtin_fmaf(x[p].z, w2, agg);
                agg = __builtin_fmaf(x[p].w, w3, agg);
                float a = tanh_sc(__builtin_fmaf(r2, agg, b2));
                acc[p][0] = __builtin_fmaf(a, wr0, acc[p][0]);
                acc[p][1] = __builtin_fmaf(a, wr1, acc[p][1]);
                acc[p][2] = __builtin_fmaf(a, wr2, acc[p][2]);
            }
        }
#pragma unroll
        for (int p = 0; p < P; ++p)
#pragma unroll
            for (int c = 0; c < NOUT; ++c) {
                const float* q = pk + c * PKW;
                res[p][c] = tanh_sc(__builtin_fmaf(q[4], acc[p][c], q[5]));
            }
    } else if (np <= 0) {
#pragma unroll
        for (int p = 0; p < P; ++p)
#pragma unroll
            for (int c = 0; c < NOUT; ++c) res[p][c] = 0.f;
    } else if (np == 1) {
#pragma unroll
        for (int p = 0; p < P; ++p)
#pragma unroll
            for (int c = 0; c < NOUT; ++c) {
                const float* q = pk + c * PKW;
                float agg = x[p].x * q[0];
                agg = __builtin_fmaf(x[p].y, q[1], agg);
                agg = __builtin_fmaf(x[p].z, q[2], agg);
                agg = __builtin_fmaf(x[p].w, q[3], agg);
                res[p][c] = tanh_sc(__builtin_fmaf(q[4], agg, q[5]));
            }
    } else {
        // ---- COLD general path (np >= 3): unroll-1 + runtime indexing so
        // arrays live in scratch and do NOT inflate hot-path registers ----
#pragma unroll
        for (int p = 0; p < P; ++p) {
            float act[NN];
            #pragma unroll 1
            for (int j = 0; j < NN; ++j) {
                const float* q = pk + j * PKW;
                float agg = x[p].x * q[0];
                agg = __builtin_fmaf(x[p].y, q[1], agg);
                agg = __builtin_fmaf(x[p].z, q[2], agg);
                agg = __builtin_fmaf(x[p].w, q[3], agg);
                act[j] = tanh_sc(__builtin_fmaf(q[4], agg, q[5]));
            }
            #pragma unroll 1
            for (int t = 1; t < np - 1; ++t) {
                float na[NN];
                #pragma unroll 1
                for (int j = 0; j < NN; ++j) {
                    const float* q = pk + j * PKW;
                    float agg = x[p].x * q[0];
                    agg = __builtin_fmaf(x[p].y, q[1], agg);
                    agg = __builtin_fmaf(x[p].z, q[2], agg);
                    agg = __builtin_fmaf(x[p].w, q[3], agg);
                    #pragma unroll 1
                    for (int k = 0; k < NN; ++k)
                        agg = __builtin_fmaf(act[k], Wrec[k*NN + j], agg);
                    na[j] = tanh_sc(__builtin_fmaf(q[4], agg, q[5]));
                }
                #pragma unroll 1
                for (int j = 0; j < NN; ++j) act[j] = na[j];
            }
            #pragma unroll
            for (int c = 0; c < NOUT; ++c) {
                const float* q = pk + c * PKW;
                float agg = x[p].x * q[0];
                agg = __builtin_fmaf(x[p].y, q[1], agg);
                agg = __builtin_fmaf(x[p].z, q[2], agg);
                agg = __builtin_fmaf(x[p].w, q[3], agg);
                #pragma unroll 1
                for (int k = 0; k < NN; ++k)
                    agg = __builtin_fmaf(act[k], Wrec[k*NN + c], agg);
                res[p][c] = tanh_sc(__builtin_fmaf(q[4], agg, q[5]));
            }
        }
    }

#pragma unroll
    for (int p = 0; p < P; ++p)
        if (pix[p] < total) {
            out[pix[p]*NOUT + 0] = res[p][0];
            out[pix[p]*NOUT + 1] = res[p][1];
            out[pix[p]*NOUT + 2] = res[p][2];
        }
}

// ---------- fallback (ws too small): round-1 style, self-contained ----------
__global__ __launch_bounds__(256)
void rnn_fallback(const float* __restrict__ inputs,
                  const float* __restrict__ Win,
                  const float* __restrict__ Wrec,
                  const float* __restrict__ bias,
                  const float* __restrict__ resp,
                  const float* __restrict__ hasin,
                  const int*   __restrict__ np_ptr,
                  float*       __restrict__ out, int total)
{
    int pix = blockIdx.x * blockDim.x + threadIdx.x;
    if (pix >= total) return;
    const int np = np_ptr[0];
    const float4 x = reinterpret_cast<const float4*>(inputs)[pix];
    float act[NN];
    #pragma unroll 1
    for (int j = 0; j < NN; ++j) act[j] = 0.f;
    #pragma unroll 1
    for (int t = 0; t < np; ++t) {
        float na[NN];
        #pragma unroll 1
        for (int j = 0; j < NN; ++j) {
            float agg = x.x * Win[0*NN+j];
            agg = __builtin_fmaf(x.y, Win[1*NN+j], agg);
            agg = __builtin_fmaf(x.z, Win[2*NN+j], agg);
            agg = __builtin_fmaf(x.w, Win[3*NN+j], agg);
            #pragma unroll 1
            for (int k = 0; k < NN; ++k)
                agg = __builtin_fmaf(act[k], Wrec[k*NN + j], agg);
            na[j] = hasin[j] * tanh_sc(C2 * __builtin_fmaf(resp[j], agg, bias[j]));
        }
        #pragma unroll 1
        for (int j = 0; j < NN; ++j) act[j] = na[j];
    }
    out[pix*NOUT+0] = act[0]; out[pix*NOUT+1] = act[1]; out[pix*NOUT+2] = act[2];
}

extern "C" void kernel_launch(void* const* d_in, const int* in_sizes, int n_in,
                              void* d_out, int out_size, void* d_ws, size_t ws_size,
                              hipStream_t stream) {
    const float* inputs = (const float*)d_in[0];
    const float* Win    = (const float*)d_in[1];
    const float* Wrec   = (const float*)d_in[2];
    const float* bias   = (const float*)d_in[3];
    const float* resp   = (const float*)d_in[4];
    const float* hasin  = (const float*)d_in[5];
    const int*   np     = (const int*)d_in[6];
    float*       out    = (float*)d_out;

    const int total = in_sizes[0] / NIN;   // H*W pixels

    if (ws_size >= (size_t)PK_BYTES) {
        float* pk = (float*)d_ws;
        pack_kernel<<<1, 128, 0, stream>>>(Win, Wrec, bias, resp, hasin, pk);
        constexpr int P = 2;
        const int block = 256;
        const int grid  = (total + block * P - 1) / (block * P);
        rnn_fused<P><<<grid, block, 0, stream>>>(inputs, pk, Wrec, np, out, total);
    } else {
        const int block = 256;
        const int grid  = (total + block - 1) / block;
        rnn_fallback<<<grid, block, 0, stream>>>(inputs, Win, Wrec, bias, resp,
                                                 hasin, np, out, total);
    }
}